// Round 13
// baseline (8408.196 us; speedup 1.0000x reference)
//
#include <hip/hip_runtime.h>
#include <hip/hip_bf16.h>
#include <stdint.h>

typedef float f32x4 __attribute__((ext_vector_type(4)));
typedef short bf16x8 __attribute__((ext_vector_type(8)));
typedef int   i32x4  __attribute__((ext_vector_type(4)));
typedef unsigned int u32x4 __attribute__((ext_vector_type(4)));

#define DEVINL static __device__ __forceinline__

// ---------------- problem dims ----------------
constexpr int BATCH = 256, SEQ = 512, IDIM = 512, HDIM = 512;
constexpr int NG = 8, WC = 32, RPG = 32, CPW = 16;

// ---------------- LDS map (bytes) ----------------
constexpr int WGS_OFF = 0;        // Wg stripe [32 cols][1024 k] bf16 (64KB), XOR-swizzled
constexpr int WHS_OFF = 65536;    // Wh stripe [16 cols][1024 k] bf16 (32KB)
constexpr int WO1_OFF = 98304;    // Wo1 stripe [16 cols][512 k] bf16 (16KB, cols 8..15 zero)
constexpr int XPOSE_OFF = 114688; // 2 critical waves x 640B repack buffers
constexpr int SMEM_BYTES = XPOSE_OFF + 2 * 640;   // 115968

// ---------------- ws map (bytes) ----------------
// flags per group (1024B region): fA u32[64] at +0, fB u32[64] at +256, hp u32[32] at +512
constexpr size_t WS_ZERO  = 8192;               // flag arrays (memset each call)
constexpr size_t HBF0_OFF = 8192;               // bf16 h buf0 [256][512] (256KB)
constexpr size_t HBF1_OFF = HBF0_OFF + 262144;  // bf16 h buf1
constexpr size_t RHBF_OFF = HBF1_OFF + 262144;  // bf16 r*h (single buffer, protocol-protected)
constexpr size_t WS_NEEDED = RHBF_OFF + 262144;

DEVINL short f2bf(float f) {
  uint32_t u = __float_as_uint(f);
  u += 0x7FFFu + ((u >> 16) & 1u);   // RNE
  return (short)(u >> 16);
}
DEVINL uint32_t cvtpk(float lo, float hi) {   // 2 bf16 in one instr (RNE) — r9/r11-proven
  uint32_t r;
  asm("v_cvt_pk_bf16_f32 %0, %1, %2" : "=v"(r) : "v"(lo), "v"(hi));
  return r;
}
DEVINL int wgs_off(int c, int k) { return WGS_OFF + c * 2048 + ((k * 2) ^ ((c & 7) << 4)); }
DEVINL int whs_off(int c, int k) { return WHS_OFF + c * 2048 + ((k * 2) ^ ((c & 7) << 4)); }
DEVINL int wo1_off(int c, int k) { return WO1_OFF + c * 1024 + ((k * 2) ^ ((c & 7) << 4)); }
DEVINL float sigm(float v) { return 1.f / (1.f + __expf(-v)); }
DEVINL bf16x8 asbf(i32x4 v) { return __builtin_bit_cast(bf16x8, v); }

// ---------------- flag / exchange primitives (agent scope: sc1) — r8-proven ----------------
DEVINL void flag_pub(uint32_t* p, uint32_t v) {
  asm volatile("s_waitcnt vmcnt(0) lgkmcnt(0)\n\tglobal_store_dword %0, %1, off sc1"
               :: "v"(p), "v"(v) : "memory");
}
// plain flag store (no drain) — used for head progress, which signals a completed READ
DEVINL void flag_raw(uint32_t* p, uint32_t v) {
  asm volatile("global_store_dword %0, %1, off sc1" :: "v"(p), "v"(v) : "memory");
}
// poll a 32-slot region (2 cache lines). Throttled + bounded.
DEVINL void poll32(const uint32_t* base, uint32_t target) {
  const uint32_t* p = base + (threadIdx.x & 31);
  int iter = 0;
  for (;;) {
    uint32_t v;
    asm volatile("global_load_dword %0, %1, off sc1\n\ts_waitcnt vmcnt(0)"
                 : "=v"(v) : "v"(p) : "memory");
    if (__all((int)(v >= target))) break;
    if (++iter > 20000) break;           // bounded: pathology -> fast fail, not timeout
    __builtin_amdgcn_s_sleep(1);         // throttle the fabric read-storm
  }
  __builtin_amdgcn_sched_barrier(0);
}
// dual poll: lanes 0-31 check baseA slots >= tA; lanes 32-63 check baseH slots >= tH.
// Same load count as poll32 (the upper lanes previously just duplicated).
DEVINL void pollA_dual(const uint32_t* baseA, const uint32_t* baseH,
                       uint32_t tA, uint32_t tH) {
  const int l = threadIdx.x & 63;
  const uint32_t* p = (l < 32) ? (baseA + l) : (baseH + (l - 32));
  const uint32_t tgt = (l < 32) ? tA : tH;
  int iter = 0;
  for (;;) {
    uint32_t v;
    asm volatile("global_load_dword %0, %1, off sc1\n\ts_waitcnt vmcnt(0)"
                 : "=v"(v) : "v"(p) : "memory");
    if (__all((int)(v >= tgt))) break;
    if (++iter > 20000) break;
    __builtin_amdgcn_s_sleep(1);
  }
  __builtin_amdgcn_sched_barrier(0);
}
// poll a full 64-slot region (head wave)
DEVINL void poll64(const uint32_t* base, uint32_t target) {
  const uint32_t* p = base + (threadIdx.x & 63);
  int iter = 0;
  for (;;) {
    uint32_t v;
    asm volatile("global_load_dword %0, %1, off sc1\n\ts_waitcnt vmcnt(0)"
                 : "=v"(v) : "v"(p) : "memory");
    if (__all((int)(v >= target))) break;
    if (++iter > 40000) break;
    __builtin_amdgcn_s_sleep(1);
  }
  __builtin_amdgcn_sched_barrier(0);
}
// repack 16x16 bf16 tile through private LDS slice -> 8B/lane store (issue only)
DEVINL void publish16x16(char* smem, int xpose, short* dst, int grow, int colbase,
                         int lane, const float* vals) {
  const int q = lane >> 4, lc = lane & 15;
#pragma unroll
  for (int ri = 0; ri < 4; ++ri)
    *(short*)(smem + xpose + (q * 4 + ri) * 40 + lc * 2) = f2bf(vals[ri]);
  asm volatile("s_waitcnt lgkmcnt(0)" ::: "memory");
  __builtin_amdgcn_sched_barrier(0);
  const int rl = lane >> 2, cq = lane & 3;
  unsigned long long d = *(const unsigned long long*)(smem + xpose + rl * 40 + cq * 8);
  short* gp = dst + (size_t)(grow + rl) * HDIM + colbase + cq * 4;
  asm volatile("global_store_dwordx2 %0, %1, off sc1" :: "v"(gp), "v"(d) : "memory");
}
// exchange-fragment gathers (sc1) — 16 x 16B, one fence
#define GLD16(dst, ptr, imm) \
  asm volatile("global_load_dwordx4 %0, %1, off offset:" imm " sc1" : "=v"(dst) : "v"(ptr))
#define GLD_ALL16(arr, ptr) do { \
  GLD16(arr[0],  ptr, "0");   GLD16(arr[1],  ptr, "64");  \
  GLD16(arr[2],  ptr, "128"); GLD16(arr[3],  ptr, "192"); \
  GLD16(arr[4],  ptr, "256"); GLD16(arr[5],  ptr, "320"); \
  GLD16(arr[6],  ptr, "384"); GLD16(arr[7],  ptr, "448"); \
  GLD16(arr[8],  ptr, "512"); GLD16(arr[9],  ptr, "576"); \
  GLD16(arr[10], ptr, "640"); GLD16(arr[11], ptr, "704"); \
  GLD16(arr[12], ptr, "768"); GLD16(arr[13], ptr, "832"); \
  GLD16(arr[14], ptr, "896"); GLD16(arr[15], ptr, "960"); \
  asm volatile("s_waitcnt vmcnt(0)" ::: "memory"); \
  __builtin_amdgcn_sched_barrier(0); \
} while (0)

#define MFMA(a, b, c) __builtin_amdgcn_mfma_f32_16x16x32_bf16((a), (b), (c), 0, 0, 0)
#define LDB(off) (*(const bf16x8*)(smem + (off)))

// x(tt) -> bf16 A-frags (plain C loads; compiler schedules waits before cvts)
#define LOADCVT_X(tt) do { \
  const float* xr_ = x + ((size_t)(rowbase + arow) * SEQ + (size_t)(tt)) * IDIM + kl; \
  _Pragma("unroll") \
  for (int ks = 0; ks < 16; ++ks) { \
    float4 a_ = *(const float4*)(xr_ + ks * 32); \
    float4 b_ = *(const float4*)(xr_ + ks * 32 + 4); \
    u32x4 v_ = {cvtpk(a_.x, a_.y), cvtpk(a_.z, a_.w), \
                cvtpk(b_.x, b_.y), cvtpk(b_.z, b_.w)}; \
    xa[ks] = __builtin_bit_cast(bf16x8, v_); \
  } \
} while (0)

__global__ void __launch_bounds__(256, 1) init_ys_kernel(float* out, const float* bo2) {
  int i = blockIdx.x * 256 + threadIdx.x;
  if (i < BATCH * SEQ) out[i] = bo2[0];
}

__global__ void __launch_bounds__(192, 1) gru_persist(
    const float* __restrict__ x,  const float* __restrict__ Wg, const float* __restrict__ bg,
    const float* __restrict__ Wh, const float* __restrict__ bh,
    const float* __restrict__ Wo1,const float* __restrict__ bo1,
    const float* __restrict__ Wo2,const float* __restrict__ bo2,
    float* __restrict__ out, char* __restrict__ ws)
{
  extern __shared__ char smem[];
  const int bid  = blockIdx.x;
  const int gi   = bid & 7;        // group; bid&7 keeps group's x rows on one XCD L2 (perf-only)
  const int j    = bid >> 3;       // 0..31 within group
  const int tid  = threadIdx.x;
  const int lane = tid & 63;
  const int wave = tid >> 6;       // 0,1 = critical (mt); 2 = head
  const int rowbase = gi * RPG;
  const int colbase = j * CPW;

  short* hbf0 = (short*)(ws + HBF0_OFF);
  short* hbf1 = (short*)(ws + HBF1_OFF);
  short* rhbf = (short*)(ws + RHBF_OFF);
  uint32_t* fA = (uint32_t*)(ws + (size_t)gi * 1024);
  uint32_t* fB = (uint32_t*)(ws + (size_t)gi * 1024 + 256);
  uint32_t* hp = (uint32_t*)(ws + (size_t)gi * 1024 + 512);   // head progress [32]

  // ---------------- init: weights -> LDS (192 threads, strided, one-time) ----------------
  for (int idx = tid; idx < 32 * 1024; idx += 192) {
    int cc = idx & 31, k = idx >> 5;
    int cg = (cc < 16) ? (colbase + cc) : (512 + colbase + (cc - 16));
    *(short*)(smem + wgs_off(cc, k)) = f2bf(Wg[(size_t)k * 1024 + cg]);
  }
  for (int idx = tid; idx < 16 * 1024; idx += 192) {
    int cc = idx & 15, k = idx >> 4;
    *(short*)(smem + whs_off(cc, k)) = f2bf(Wh[(size_t)k * 512 + colbase + cc]);
  }
  for (int idx = tid; idx < 16 * 512; idx += 192) {
    int cc = idx & 15, k = idx >> 4;
    *(short*)(smem + wo1_off(cc, k)) = (cc < 8) ? f2bf(Wo1[(size_t)k * 256 + j * 8 + cc]) : (short)0;
  }

  const int lc = lane & 15;
  const int kl = (lane >> 4) * 8;          // frag k sub-offset (elements)
  const float bgu  = bg[colbase + lc];
  const float bgr  = bg[512 + colbase + lc];
  const float bhc  = bh[colbase + lc];
  const float bo1c = (lc < 8) ? bo1[j * 8 + lc] : 0.f;
  const float wo2c = (lc < 8) ? Wo2[j * 8 + lc] : 0.f;
  __syncthreads();   // the ONLY block barrier

  if (wave == 2) {
    // ======= head wave: y outputs off the critical path (race-free via dbuf + hp) =======
    const size_t ro0 = (size_t)(rowbase + lc) * HDIM + kl;
    const size_t ro1 = ro0 + (size_t)16 * HDIM;
    uint32_t* myhp = hp + j;
    for (int t = 1; t <= SEQ; ++t) {
      poll64(fB, (uint32_t)t);             // h(t-1) from all 64 producer waves
      const short* hb = ((t - 1) & 1) ? hbf1 : hbf0;
      i32x4 ha0[16], ha1[16];
      GLD_ALL16(ha0, (const char*)(hb + ro0));
      GLD_ALL16(ha1, (const char*)(hb + ro1));
      flag_raw(myhp, (uint32_t)t);         // gather done -> unblock producers of h(t+1)
      f32x4 hd0 = {0,0,0,0}, hd1 = {0,0,0,0};
#pragma unroll
      for (int ks = 0; ks < 16; ks += 2) {
        hd0 = MFMA(asbf(ha0[ks]),   LDB(wo1_off(lc, ks * 32 + kl)),       hd0);
        hd0 = MFMA(asbf(ha0[ks+1]), LDB(wo1_off(lc, (ks + 1) * 32 + kl)), hd0);
        hd1 = MFMA(asbf(ha1[ks]),   LDB(wo1_off(lc, ks * 32 + kl)),       hd1);
        hd1 = MFMA(asbf(ha1[ks+1]), LDB(wo1_off(lc, (ks + 1) * 32 + kl)), hd1);
      }
#pragma unroll
      for (int ri = 0; ri < 4; ++ri) {
        float z0 = fmaxf(hd0[ri] + bo1c, 0.f) * wo2c;
        float z1 = fmaxf(hd1[ri] + bo1c, 0.f) * wo2c;
        z0 += __shfl_xor(z0, 1); z0 += __shfl_xor(z0, 2);
        z0 += __shfl_xor(z0, 4); z0 += __shfl_xor(z0, 8);
        z1 += __shfl_xor(z1, 1); z1 += __shfl_xor(z1, 2);
        z1 += __shfl_xor(z1, 4); z1 += __shfl_xor(z1, 8);
        if (lc == 0) {
          int r0 = rowbase + (lane >> 4) * 4 + ri;
          unsafeAtomicAdd(&out[(size_t)r0 * SEQ + (t - 1)], z0);
          unsafeAtomicAdd(&out[(size_t)(r0 + 16) * SEQ + (t - 1)], z1);
        }
      }
    }
    return;
  }

  // ================= critical waves (mt = wave 0,1): the recurrence =================
  const int mt    = wave;
  const int arow  = mt * 16 + lc;          // A-frag row (local)
  const int xpose = XPOSE_OFF + mt * 640;
  const int grow  = rowbase + mt * 16;
  const uint32_t* fAmine = fA + mt * 32;
  const uint32_t* fBmine = fB + mt * 32;
  uint32_t* myA = fA + (mt * 32 + j);
  uint32_t* myB = fB + (mt * 32 + j);

  const size_t hro = (size_t)(rowbase + arow) * HDIM + kl;
  const char* hfrag0 = (const char*)(hbf0 + hro);
  const char* hfrag1 = (const char*)(hbf1 + hro);
  const char* rhfrag = (const char*)(rhbf + hro);

  bf16x8 xa[16];
  float hreg[4] = {0.f, 0.f, 0.f, 0.f};

  for (int t = 0; t < SEQ; ++t) {
    // ---- x A-frags + gates-x MFMAs (consumer-side filler, r8 position) ----
    LOADCVT_X(t);
    f32x4 gu0 = {0,0,0,0}, gu1 = {0,0,0,0}, gr0 = {0,0,0,0}, gr1 = {0,0,0,0};
#pragma unroll
    for (int ks = 0; ks < 16; ks += 2) {
      gu0 = MFMA(xa[ks],   LDB(wgs_off(lc, ks * 32 + kl)),            gu0);
      gu1 = MFMA(xa[ks+1], LDB(wgs_off(lc, (ks + 1) * 32 + kl)),      gu1);
      gr0 = MFMA(xa[ks],   LDB(wgs_off(16 + lc, ks * 32 + kl)),       gr0);
      gr1 = MFMA(xa[ks+1], LDB(wgs_off(16 + lc, (ks + 1) * 32 + kl)), gr1);
    }
    // ---- hop B: h_{t-1} -> RESET gate first (shortest path to flagA) ----
    i32x4 ha[16];
    if (t) {
      poll32(fBmine, (uint32_t)t);
      GLD_ALL16(ha, ((t - 1) & 1) ? hfrag1 : hfrag0);
#pragma unroll
      for (int ks = 0; ks < 16; ks += 2) {
        gr0 = MFMA(asbf(ha[ks]),   LDB(wgs_off(16 + lc, 512 + ks * 32 + kl)),       gr0);
        gr1 = MFMA(asbf(ha[ks+1]), LDB(wgs_off(16 + lc, 512 + (ks + 1) * 32 + kl)), gr1);
      }
    }
    f32x4 gr = gr0 + gr1;
    float rhv[4];
#pragma unroll
    for (int ri = 0; ri < 4; ++ri) rhv[ri] = sigm(gr[ri] + bgr) * hreg[ri];
    if (t) {
      publish16x16(smem, xpose, rhbf, grow, colbase, lane, rhv);
      flag_pub(myA, (uint32_t)(t + 1));       // flag ASAP; movable work goes after
    }
    // ---- pollA-window filler: update-gate h-part + cand-x MFMAs ----
    if (t) {
#pragma unroll
      for (int ks = 0; ks < 16; ks += 2) {
        gu0 = MFMA(asbf(ha[ks]),   LDB(wgs_off(lc, 512 + ks * 32 + kl)),       gu0);
        gu1 = MFMA(asbf(ha[ks+1]), LDB(wgs_off(lc, 512 + (ks + 1) * 32 + kl)), gu1);
      }
    }
    f32x4 gu = gu0 + gu1;
    float uv[4];
#pragma unroll
    for (int ri = 0; ri < 4; ++ri) uv[ri] = sigm(gu[ri] + bgu);
    f32x4 cx0 = {0,0,0,0}, cx1 = {0,0,0,0};
#pragma unroll
    for (int ks = 0; ks < 16; ks += 2) {
      cx0 = MFMA(xa[ks],   LDB(whs_off(lc, ks * 32 + kl)),       cx0);
      cx1 = MFMA(xa[ks+1], LDB(whs_off(lc, (ks + 1) * 32 + kl)), cx1);
    }
    // ---- hop A: r*h ready AND heads done with h(t-2) (merged dual poll) ----
    f32x4 ch0 = {0,0,0,0}, ch1 = {0,0,0,0};
    if (t) {
      pollA_dual(fAmine, hp, (uint32_t)(t + 1), (uint32_t)(t - 1));
      i32x4 ra[16];
      GLD_ALL16(ra, rhfrag);
#pragma unroll
      for (int ks = 0; ks < 16; ks += 2) {
        ch0 = MFMA(asbf(ra[ks]),   LDB(whs_off(lc, 512 + ks * 32 + kl)),       ch0);
        ch1 = MFMA(asbf(ra[ks+1]), LDB(whs_off(lc, 512 + (ks + 1) * 32 + kl)), ch1);
      }
    }
    // ---- h update ----
    f32x4 cc = cx0 + cx1 + ch0 + ch1;
    float hnv[4];
#pragma unroll
    for (int ri = 0; ri < 4; ++ri) {
      float cand = tanhf(cc[ri] + bhc);
      float hnew = hreg[ri] + uv[ri] * (cand - hreg[ri]);
      hreg[ri] = hnew; hnv[ri] = hnew;
      if (t == SEQ - 1) {
        int row = mt * 16 + (lane >> 4) * 4 + ri;
        out[(size_t)(BATCH * SEQ) + (size_t)(rowbase + row) * HDIM + colbase + lc] = hnew;
      }
    }
    // ---- publish h into buffer t&1, flag immediately ----
    publish16x16(smem, xpose, (t & 1) ? hbf1 : hbf0, grow, colbase, lane, hnv);
    flag_pub(myB, (uint32_t)(t + 1));
  }
}

extern "C" void kernel_launch(void* const* d_in, const int* in_sizes, int n_in,
                              void* d_out, int out_size, void* d_ws, size_t ws_size,
                              hipStream_t stream) {
  const float* x   = (const float*)d_in[0];
  const float* Wg  = (const float*)d_in[1];
  const float* bg  = (const float*)d_in[2];
  const float* Wh  = (const float*)d_in[3];
  const float* bh  = (const float*)d_in[4];
  const float* Wo1 = (const float*)d_in[5];
  const float* bo1 = (const float*)d_in[6];
  const float* Wo2 = (const float*)d_in[7];
  const float* bo2 = (const float*)d_in[8];
  float* out = (float*)d_out;
  char*  ws  = (char*)d_ws;
  if (ws_size < WS_NEEDED) return;

  hipMemsetAsync(ws, 0, WS_ZERO, stream);      // flag arrays (fA/fB/hp)
  init_ys_kernel<<<dim3(512), dim3(256), 0, stream>>>(out, bo2);

  (void)hipFuncSetAttribute((const void*)gru_persist,
                            hipFuncAttributeMaxDynamicSharedMemorySize, SMEM_BYTES);

  // 256 blocks x ~113KB LDS -> 1 block/CU, all co-resident (proven r2-r12).
  gru_persist<<<dim3(NG * WC), dim3(192), SMEM_BYTES, stream>>>(
      x, Wg, bg, Wh, bh, Wo1, bo1, Wo2, bo2, out, ws);
}

// Round 14
// 7786.975 us; speedup vs baseline: 1.0798x; 1.0798x over previous
//
#include <hip/hip_runtime.h>
#include <hip/hip_bf16.h>
#include <stdint.h>

typedef float f32x4 __attribute__((ext_vector_type(4)));
typedef short bf16x8 __attribute__((ext_vector_type(8)));
typedef int   i32x4  __attribute__((ext_vector_type(4)));
typedef unsigned int u32x4 __attribute__((ext_vector_type(4)));

#define DEVINL static __device__ __forceinline__

// ---------------- problem dims ----------------
constexpr int BATCH = 256, SEQ = 512, IDIM = 512, HDIM = 512;
constexpr int NG = 8, WC = 32, RPG = 32, CPW = 16;

// ---------------- LDS map (bytes) ----------------
constexpr int WGS_OFF = 0;        // Wg stripe [32 cols][1024 k] bf16 (64KB), XOR-swizzled
constexpr int WHS_OFF = 65536;    // Wh stripe [16 cols][1024 k] bf16 (32KB)
constexpr int WO1_OFF = 98304;    // Wo1 stripe [16 cols][512 k] bf16 (16KB, cols 8..15 zero)
constexpr int XPOSE_OFF = 114688; // 2 waves x 640B repack buffers
constexpr int SMEM_BYTES = XPOSE_OFF + 2 * 640;   // 115968

// ---------------- ws map (bytes) ----------------
// flags per group (512B region): fA u32[mt*32+j] at +0, fB at +256
constexpr size_t WS_ZERO  = 4096;             // flag arrays (memset each call)
constexpr size_t HBF_OFF  = 8192;             // bf16 h   [256][512] (256KB), no init needed
constexpr size_t RHBF_OFF = HBF_OFF + 262144; // bf16 r*h [256][512] (256KB), no init needed
constexpr size_t WS_ATOM  = RHBF_OFF + 262144;        // r8 footprint (~0.53MB)
constexpr size_t YP_OFF   = WS_ATOM;                  // fp32 partials [256][512][32] (16.8MB)
constexpr size_t WS_PART  = YP_OFF + (size_t)BATCH * SEQ * 32 * 4;

DEVINL short f2bf(float f) {
  uint32_t u = __float_as_uint(f);
  u += 0x7FFFu + ((u >> 16) & 1u);   // RNE
  return (short)(u >> 16);
}
DEVINL uint32_t cvtpk(float lo, float hi) {   // 2 bf16 in one instr (RNE) — r9/r11/r13-proven
  uint32_t r;
  asm("v_cvt_pk_bf16_f32 %0, %1, %2" : "=v"(r) : "v"(lo), "v"(hi));
  return r;
}
DEVINL int wgs_off(int c, int k) { return WGS_OFF + c * 2048 + ((k * 2) ^ ((c & 7) << 4)); }
DEVINL int whs_off(int c, int k) { return WHS_OFF + c * 2048 + ((k * 2) ^ ((c & 7) << 4)); }
DEVINL int wo1_off(int c, int k) { return WO1_OFF + c * 1024 + ((k * 2) ^ ((c & 7) << 4)); }
DEVINL float sigm(float v) { return 1.f / (1.f + __expf(-v)); }
DEVINL bf16x8 asbf(i32x4 v) { return __builtin_bit_cast(bf16x8, v); }

// ---------------- flag / exchange primitives (agent scope: sc1) — r8-proven ----------------
DEVINL void flag_pub(uint32_t* p, uint32_t v) {
  asm volatile("s_waitcnt vmcnt(0) lgkmcnt(0)\n\tglobal_store_dword %0, %1, off sc1"
               :: "v"(p), "v"(v) : "memory");
}
// poll own 32-slot region (2 cache lines). Throttled + bounded.
DEVINL void poll32(const uint32_t* base, uint32_t target) {
  const uint32_t* p = base + (threadIdx.x & 31);
  int iter = 0;
  for (;;) {
    uint32_t v;
    asm volatile("global_load_dword %0, %1, off sc1\n\ts_waitcnt vmcnt(0)"
                 : "=v"(v) : "v"(p) : "memory");
    if (__all((int)(v >= target))) break;
    if (++iter > 20000) break;           // bounded: pathology -> fast fail, not timeout
    __builtin_amdgcn_s_sleep(1);         // throttle the fabric read-storm
  }
  __builtin_amdgcn_sched_barrier(0);
}
// repack 16x16 bf16 tile through private LDS slice -> 8B/lane store (issue only)
DEVINL void publish16x16(char* smem, int xpose, short* dst, int grow, int colbase,
                         int lane, const float* vals) {
  const int q = lane >> 4, lc = lane & 15;
#pragma unroll
  for (int ri = 0; ri < 4; ++ri)
    *(short*)(smem + xpose + (q * 4 + ri) * 40 + lc * 2) = f2bf(vals[ri]);
  asm volatile("s_waitcnt lgkmcnt(0)" ::: "memory");
  __builtin_amdgcn_sched_barrier(0);
  const int rl = lane >> 2, cq = lane & 3;
  unsigned long long d = *(const unsigned long long*)(smem + xpose + rl * 40 + cq * 8);
  short* gp = dst + (size_t)(grow + rl) * HDIM + colbase + cq * 4;
  asm volatile("global_store_dwordx2 %0, %1, off sc1" :: "v"(gp), "v"(d) : "memory");
}
// exchange-fragment gathers (sc1) — 16 x 16B, one fence
#define GLD16(dst, ptr, imm) \
  asm volatile("global_load_dwordx4 %0, %1, off offset:" imm " sc1" : "=v"(dst) : "v"(ptr))
#define GLD_ALL16(arr, ptr) do { \
  GLD16(arr[0],  ptr, "0");   GLD16(arr[1],  ptr, "64");  \
  GLD16(arr[2],  ptr, "128"); GLD16(arr[3],  ptr, "192"); \
  GLD16(arr[4],  ptr, "256"); GLD16(arr[5],  ptr, "320"); \
  GLD16(arr[6],  ptr, "384"); GLD16(arr[7],  ptr, "448"); \
  GLD16(arr[8],  ptr, "512"); GLD16(arr[9],  ptr, "576"); \
  GLD16(arr[10], ptr, "640"); GLD16(arr[11], ptr, "704"); \
  GLD16(arr[12], ptr, "768"); GLD16(arr[13], ptr, "832"); \
  GLD16(arr[14], ptr, "896"); GLD16(arr[15], ptr, "960"); \
  asm volatile("s_waitcnt vmcnt(0)" ::: "memory"); \
  __builtin_amdgcn_sched_barrier(0); \
} while (0)

#define MFMA(a, b, c) __builtin_amdgcn_mfma_f32_16x16x32_bf16((a), (b), (c), 0, 0, 0)
#define LDB(off) (*(const bf16x8*)(smem + (off)))

// x(tt) -> bf16 A-frags (plain C loads; compiler schedules waits before cvts)
#define LOADCVT_X(tt) do { \
  const float* xr_ = x + ((size_t)(rowbase + arow) * SEQ + (size_t)(tt)) * IDIM + kl; \
  _Pragma("unroll") \
  for (int ks = 0; ks < 16; ++ks) { \
    float4 a_ = *(const float4*)(xr_ + ks * 32); \
    float4 b_ = *(const float4*)(xr_ + ks * 32 + 4); \
    u32x4 v_ = {cvtpk(a_.x, a_.y), cvtpk(a_.z, a_.w), \
                cvtpk(b_.x, b_.y), cvtpk(b_.z, b_.w)}; \
    xa[ks] = __builtin_bit_cast(bf16x8, v_); \
  } \
} while (0)

__global__ void __launch_bounds__(256, 1) init_ys_kernel(float* out, const float* bo2) {
  int i = blockIdx.x * 256 + threadIdx.x;
  if (i < BATCH * SEQ) out[i] = bo2[0];
}

// finalize (PART path): out[e] = bo2 + sum_j part[e*32+j]; one thread per (b,t)
__global__ void __launch_bounds__(256, 1) finalize_ys_kernel(
    const float* __restrict__ part, float* __restrict__ out, const float* __restrict__ bo2) {
  int e = blockIdx.x * 256 + threadIdx.x;           // 512 blocks x 256 = BATCH*SEQ
  const float4* p = (const float4*)(part + (size_t)e * 32);
  float s = 0.f;
#pragma unroll
  for (int q = 0; q < 8; ++q) { float4 v = p[q]; s += v.x + v.y + v.z + v.w; }
  out[e] = bo2[0] + s;
}

template<bool PART>
__global__ void __launch_bounds__(128, 1) gru_persist(
    const float* __restrict__ x,  const float* __restrict__ Wg, const float* __restrict__ bg,
    const float* __restrict__ Wh, const float* __restrict__ bh,
    const float* __restrict__ Wo1,const float* __restrict__ bo1,
    const float* __restrict__ Wo2,const float* __restrict__ bo2,
    float* __restrict__ out, char* __restrict__ ws, float* __restrict__ ypart)
{
  extern __shared__ char smem[];
  const int bid  = blockIdx.x;
  const int gi   = bid & 7;        // group; bid&7 keeps group's x rows on one XCD L2 (perf-only)
  const int j    = bid >> 3;       // 0..31 within group
  const int tid  = threadIdx.x;
  const int lane = tid & 63;
  const int mt   = tid >> 6;       // wave 0,1 = M-tile
  const int rowbase = gi * RPG;
  const int colbase = j * CPW;

  short* hbf  = (short*)(ws + HBF_OFF);
  short* rhbf = (short*)(ws + RHBF_OFF);
  uint32_t* fA = (uint32_t*)(ws + (size_t)gi * 512);
  uint32_t* fB = (uint32_t*)(ws + (size_t)gi * 512 + 256);
  const uint32_t* fAmine = fA + mt * 32;   // this wave's producers (same mt-half)
  const uint32_t* fBmine = fB + mt * 32;
  uint32_t* myA = fA + (mt * 32 + j);
  uint32_t* myB = fB + (mt * 32 + j);

  // ---------------- init: weights -> LDS (128 threads, one-time) ----------------
  for (int it = 0; it < 256; ++it) {
    int cc = tid & 31;
    int k = (tid >> 5) + it * 4;
    int cg = (cc < 16) ? (colbase + cc) : (512 + colbase + (cc - 16));
    *(short*)(smem + wgs_off(cc, k)) = f2bf(Wg[(size_t)k * 1024 + cg]);
  }
  for (int it = 0; it < 128; ++it) {
    int cc = tid & 15;
    int k = (tid >> 4) + it * 8;
    *(short*)(smem + whs_off(cc, k)) = f2bf(Wh[(size_t)k * 512 + colbase + cc]);
  }
  for (int it = 0; it < 64; ++it) {
    int cc = tid & 15;
    int k = (tid >> 4) + it * 8;
    *(short*)(smem + wo1_off(cc, k)) = (cc < 8) ? f2bf(Wo1[(size_t)k * 256 + j * 8 + cc]) : (short)0;
  }

  const int lc = lane & 15;
  const float bgu  = bg[colbase + lc];
  const float bgr  = bg[512 + colbase + lc];
  const float bhc  = bh[colbase + lc];
  const float bo1c = (lc < 8) ? bo1[j * 8 + lc] : 0.f;
  const float wo2c = (lc < 8) ? Wo2[j * 8 + lc] : 0.f;
  __syncthreads();   // the ONLY block barrier

  const int arow  = mt * 16 + lc;          // A-frag row (local)
  const int kl    = (lane >> 4) * 8;       // frag k sub-offset (elements)
  const int xpose = XPOSE_OFF + mt * 640;
  const int grow  = rowbase + mt * 16;

  const char* hfrag  = (const char*)(hbf  + (size_t)(rowbase + arow) * HDIM + kl);
  const char* rhfrag = (const char*)(rhbf + (size_t)(rowbase + arow) * HDIM + kl);

  bf16x8 xa[16];
  float hreg[4] = {0.f, 0.f, 0.f, 0.f};
  for (int t = 0; t < SEQ; ++t) {
    // ---- x A-frags + gates-x MFMAs (overlap the fB wait window) ----
    LOADCVT_X(t);
    f32x4 gu0 = {0,0,0,0}, gu1 = {0,0,0,0}, gr0 = {0,0,0,0}, gr1 = {0,0,0,0};
#pragma unroll
    for (int ks = 0; ks < 16; ks += 2) {
      gu0 = MFMA(xa[ks],   LDB(wgs_off(lc, ks * 32 + kl)),            gu0);
      gu1 = MFMA(xa[ks+1], LDB(wgs_off(lc, (ks + 1) * 32 + kl)),      gu1);
      gr0 = MFMA(xa[ks],   LDB(wgs_off(16 + lc, ks * 32 + kl)),       gr0);
      gr1 = MFMA(xa[ks+1], LDB(wgs_off(16 + lc, (ks + 1) * 32 + kl)), gr1);
    }
    // ---- hop B: h_{t-1} ----
    i32x4 ha[16];
    if (t) {
      poll32(fBmine, (uint32_t)t);
      GLD_ALL16(ha, hfrag);
#pragma unroll
      for (int ks = 0; ks < 16; ks += 2) {
        gu0 = MFMA(asbf(ha[ks]),   LDB(wgs_off(lc, 512 + ks * 32 + kl)),            gu0);
        gu1 = MFMA(asbf(ha[ks+1]), LDB(wgs_off(lc, 512 + (ks + 1) * 32 + kl)),      gu1);
        gr0 = MFMA(asbf(ha[ks]),   LDB(wgs_off(16 + lc, 512 + ks * 32 + kl)),       gr0);
        gr1 = MFMA(asbf(ha[ks+1]), LDB(wgs_off(16 + lc, 512 + (ks + 1) * 32 + kl)), gr1);
      }
    }
    f32x4 gu = gu0 + gu1, gr = gr0 + gr1;
    float uv[4], rhv[4];
#pragma unroll
    for (int ri = 0; ri < 4; ++ri) {
      uv[ri]  = sigm(gu[ri] + bgu);
      rhv[ri] = sigm(gr[ri] + bgr) * hreg[ri];
    }
    if (t) {   // rh(0)=0 group-wide: no publish/consume at t=0
      publish16x16(smem, xpose, rhbf, grow, colbase, lane, rhv);
      flag_pub(myA, (uint32_t)(t + 1));
    }
    // ---- fA shadow: head MFMAs + cand-x MFMAs ----
    f32x4 hd0 = {0,0,0,0}, hd1 = {0,0,0,0};
    if (t) {
#pragma unroll
      for (int ks = 0; ks < 16; ks += 2) {
        hd0 = MFMA(asbf(ha[ks]),   LDB(wo1_off(lc, ks * 32 + kl)),       hd0);
        hd1 = MFMA(asbf(ha[ks+1]), LDB(wo1_off(lc, (ks + 1) * 32 + kl)), hd1);
      }
    }
    f32x4 cx0 = {0,0,0,0}, cx1 = {0,0,0,0};
#pragma unroll
    for (int ks = 0; ks < 16; ks += 2) {
      cx0 = MFMA(xa[ks],   LDB(whs_off(lc, ks * 32 + kl)),       cx0);
      cx1 = MFMA(xa[ks+1], LDB(whs_off(lc, (ks + 1) * 32 + kl)), cx1);
    }
    // ---- hop A: r*h ----
    f32x4 ch0 = {0,0,0,0}, ch1 = {0,0,0,0};
    if (t) {
      poll32(fAmine, (uint32_t)(t + 1));
      i32x4 ra[16];
      GLD_ALL16(ra, rhfrag);
#pragma unroll
      for (int ks = 0; ks < 16; ks += 2) {
        ch0 = MFMA(asbf(ra[ks]),   LDB(whs_off(lc, 512 + ks * 32 + kl)),       ch0);
        ch1 = MFMA(asbf(ra[ks+1]), LDB(whs_off(lc, 512 + (ks + 1) * 32 + kl)), ch1);
      }
    }
    // ---- h update ----
    f32x4 cc = cx0 + cx1 + ch0 + ch1;
    float hnv[4];
#pragma unroll
    for (int ri = 0; ri < 4; ++ri) {
      float cand = tanhf(cc[ri] + bhc);
      float hnew = hreg[ri] + uv[ri] * (cand - hreg[ri]);
      hreg[ri] = hnew; hnv[ri] = hnew;
      if (t == SEQ - 1) {
        int row = mt * 16 + (lane >> 4) * 4 + ri;
        out[(size_t)(BATCH * SEQ) + (size_t)(rowbase + row) * HDIM + colbase + lc] = hnew;
      }
    }
    publish16x16(smem, xpose, hbf, grow, colbase, lane, hnv);
    flag_pub(myB, (uint32_t)(t + 1));
    // ---- finish head y_{t-1}: shuffles + partial-store/atomic (off the drain path) ----
    if (t) {
      f32x4 d = hd0 + hd1;
#pragma unroll
      for (int ri = 0; ri < 4; ++ri) {
        float z = fmaxf(d[ri] + bo1c, 0.f) * wo2c;
        z += __shfl_xor(z, 1); z += __shfl_xor(z, 2);
        z += __shfl_xor(z, 4); z += __shfl_xor(z, 8);
        if (lc == 0) {
          int row = rowbase + mt * 16 + (lane >> 4) * 4 + ri;
          if constexpr (PART)
            ypart[((size_t)row * SEQ + (t - 1)) * 32 + j] = z;   // plain cached store
          else
            unsafeAtomicAdd(&out[(size_t)row * SEQ + (t - 1)], z);
        }
      }
    }
  }
  // ---- epilogue: y_{SEQ-1} ----
  poll32(fBmine, (uint32_t)SEQ);
  i32x4 ha[16];
  GLD_ALL16(ha, hfrag);
  f32x4 hd0 = {0,0,0,0}, hd1 = {0,0,0,0};
#pragma unroll
  for (int ks = 0; ks < 16; ks += 2) {
    hd0 = MFMA(asbf(ha[ks]),   LDB(wo1_off(lc, ks * 32 + kl)),       hd0);
    hd1 = MFMA(asbf(ha[ks+1]), LDB(wo1_off(lc, (ks + 1) * 32 + kl)), hd1);
  }
  f32x4 d = hd0 + hd1;
#pragma unroll
  for (int ri = 0; ri < 4; ++ri) {
    float z = fmaxf(d[ri] + bo1c, 0.f) * wo2c;
    z += __shfl_xor(z, 1); z += __shfl_xor(z, 2);
    z += __shfl_xor(z, 4); z += __shfl_xor(z, 8);
    if (lc == 0) {
      int row = rowbase + mt * 16 + (lane >> 4) * 4 + ri;
      if constexpr (PART)
        ypart[((size_t)row * SEQ + (SEQ - 1)) * 32 + j] = z;
      else
        unsafeAtomicAdd(&out[(size_t)row * SEQ + (SEQ - 1)], z);
    }
  }
}

extern "C" void kernel_launch(void* const* d_in, const int* in_sizes, int n_in,
                              void* d_out, int out_size, void* d_ws, size_t ws_size,
                              hipStream_t stream) {
  const float* x   = (const float*)d_in[0];
  const float* Wg  = (const float*)d_in[1];
  const float* bg  = (const float*)d_in[2];
  const float* Wh  = (const float*)d_in[3];
  const float* bh  = (const float*)d_in[4];
  const float* Wo1 = (const float*)d_in[5];
  const float* bo1 = (const float*)d_in[6];
  const float* Wo2 = (const float*)d_in[7];
  const float* bo2 = (const float*)d_in[8];
  float* out = (float*)d_out;
  char*  ws  = (char*)d_ws;
  if (ws_size < WS_ATOM) return;

  const bool part = (ws_size >= WS_PART);
  float* ypart = (float*)(ws + YP_OFF);

  hipMemsetAsync(ws, 0, WS_ZERO, stream);      // flag arrays
  if (!part)
    init_ys_kernel<<<dim3(512), dim3(256), 0, stream>>>(out, bo2);

  if (part) {
    (void)hipFuncSetAttribute((const void*)gru_persist<true>,
                              hipFuncAttributeMaxDynamicSharedMemorySize, SMEM_BYTES);
    gru_persist<true><<<dim3(NG * WC), dim3(128), SMEM_BYTES, stream>>>(
        x, Wg, bg, Wh, bh, Wo1, bo1, Wo2, bo2, out, ws, ypart);
    finalize_ys_kernel<<<dim3(512), dim3(256), 0, stream>>>(ypart, out, bo2);
  } else {
    (void)hipFuncSetAttribute((const void*)gru_persist<false>,
                              hipFuncAttributeMaxDynamicSharedMemorySize, SMEM_BYTES);
    gru_persist<false><<<dim3(NG * WC), dim3(128), SMEM_BYTES, stream>>>(
        x, Wg, bg, Wh, bh, Wo1, bo1, Wo2, bo2, out, ws, ypart);
  }
}

// Round 15
// 4348.838 us; speedup vs baseline: 1.9334x; 1.7906x over previous
//
#include <hip/hip_runtime.h>
#include <hip/hip_bf16.h>
#include <stdint.h>

typedef float f32x4 __attribute__((ext_vector_type(4)));
typedef short bf16x8 __attribute__((ext_vector_type(8)));
typedef int   i32x4  __attribute__((ext_vector_type(4)));

#define DEVINL static __device__ __forceinline__

// ---------------- problem dims ----------------
constexpr int BATCH = 256, SEQ = 512, IDIM = 512, HDIM = 512;
constexpr int NG = 8, WC = 32, RPG = 32, CPW = 16;

// ---------------- LDS map (bytes) ----------------
constexpr int WGS_OFF = 0;        // Wg stripe [32 cols][1024 k] bf16 (64KB), XOR-swizzled
constexpr int WHS_OFF = 65536;    // Wh stripe [16 cols][1024 k] bf16 (32KB)
constexpr int WO1_OFF = 98304;    // Wo1 stripe [16 cols][512 k] bf16 (16KB, cols 8..15 zero)
constexpr int XPOSE_OFF = 114688; // 2 waves x 640B repack buffers
constexpr int SMEM_BYTES = XPOSE_OFF + 2 * 640;   // 115968

// ---------------- ws map (bytes) ----------------
// flags per group (512B region): fA u32[mt*32+j] at +0, fB at +256
constexpr size_t WS_ZERO  = 4096;             // flag arrays (memset each call)
constexpr size_t HBF_OFF  = 8192;             // bf16 h   [256][512] (256KB), no init needed
constexpr size_t RHBF_OFF = HBF_OFF + 262144; // bf16 r*h [256][512] (256KB), no init needed
constexpr size_t WS_ATOM  = RHBF_OFF + 262144;        // r8 footprint (~0.53MB)
constexpr size_t YP_OFF   = WS_ATOM;                  // fp32 partials [256][512][32] (16.8MB)
constexpr size_t WS_PART  = YP_OFF + (size_t)BATCH * SEQ * 32 * 4;

DEVINL short f2bf(float f) {
  uint32_t u = __float_as_uint(f);
  u += 0x7FFFu + ((u >> 16) & 1u);   // RNE
  return (short)(u >> 16);
}
DEVINL int wgs_off(int c, int k) { return WGS_OFF + c * 2048 + ((k * 2) ^ ((c & 7) << 4)); }
DEVINL int whs_off(int c, int k) { return WHS_OFF + c * 2048 + ((k * 2) ^ ((c & 7) << 4)); }
DEVINL int wo1_off(int c, int k) { return WO1_OFF + c * 1024 + ((k * 2) ^ ((c & 7) << 4)); }
DEVINL float sigm(float v) { return 1.f / (1.f + __expf(-v)); }
DEVINL bf16x8 asbf(i32x4 v) { return __builtin_bit_cast(bf16x8, v); }

// ---------------- flag / exchange primitives (agent scope: sc1) — r8-proven ----------------
DEVINL void flag_pub(uint32_t* p, uint32_t v) {
  asm volatile("s_waitcnt vmcnt(0) lgkmcnt(0)\n\tglobal_store_dword %0, %1, off sc1"
               :: "v"(p), "v"(v) : "memory");
}
// poll own 32-slot region (2 cache lines). Throttled + bounded.
DEVINL void poll32(const uint32_t* base, uint32_t target) {
  const uint32_t* p = base + (threadIdx.x & 31);
  int iter = 0;
  for (;;) {
    uint32_t v;
    asm volatile("global_load_dword %0, %1, off sc1\n\ts_waitcnt vmcnt(0)"
                 : "=v"(v) : "v"(p) : "memory");
    if (__all((int)(v >= target))) break;
    if (++iter > 20000) break;           // bounded: pathology -> fast fail, not timeout
    __builtin_amdgcn_s_sleep(1);         // throttle the fabric read-storm
  }
  __builtin_amdgcn_sched_barrier(0);
}
// repack 16x16 bf16 tile through private LDS slice -> 8B/lane store (issue only)
DEVINL void publish16x16(char* smem, int xpose, short* dst, int grow, int colbase,
                         int lane, const float* vals) {
  const int q = lane >> 4, lc = lane & 15;
#pragma unroll
  for (int ri = 0; ri < 4; ++ri)
    *(short*)(smem + xpose + (q * 4 + ri) * 40 + lc * 2) = f2bf(vals[ri]);
  asm volatile("s_waitcnt lgkmcnt(0)" ::: "memory");
  __builtin_amdgcn_sched_barrier(0);
  const int rl = lane >> 2, cq = lane & 3;
  unsigned long long d = *(const unsigned long long*)(smem + xpose + rl * 40 + cq * 8);
  short* gp = dst + (size_t)(grow + rl) * HDIM + colbase + cq * 4;
  asm volatile("global_store_dwordx2 %0, %1, off sc1" :: "v"(gp), "v"(d) : "memory");
}
// exchange-fragment gathers (sc1) — 16 x 16B, one fence
#define GLD16(dst, ptr, imm) \
  asm volatile("global_load_dwordx4 %0, %1, off offset:" imm " sc1" : "=v"(dst) : "v"(ptr))
#define GLD_ALL16(arr, ptr) do { \
  GLD16(arr[0],  ptr, "0");   GLD16(arr[1],  ptr, "64");  \
  GLD16(arr[2],  ptr, "128"); GLD16(arr[3],  ptr, "192"); \
  GLD16(arr[4],  ptr, "256"); GLD16(arr[5],  ptr, "320"); \
  GLD16(arr[6],  ptr, "384"); GLD16(arr[7],  ptr, "448"); \
  GLD16(arr[8],  ptr, "512"); GLD16(arr[9],  ptr, "576"); \
  GLD16(arr[10], ptr, "640"); GLD16(arr[11], ptr, "704"); \
  GLD16(arr[12], ptr, "768"); GLD16(arr[13], ptr, "832"); \
  GLD16(arr[14], ptr, "896"); GLD16(arr[15], ptr, "960"); \
  asm volatile("s_waitcnt vmcnt(0)" ::: "memory"); \
  __builtin_amdgcn_sched_barrier(0); \
} while (0)

#define MFMA(a, b, c) __builtin_amdgcn_mfma_f32_16x16x32_bf16((a), (b), (c), 0, 0, 0)
#define LDB(off) (*(const bf16x8*)(smem + (off)))

__global__ void __launch_bounds__(256, 1) init_ys_kernel(float* out, const float* bo2) {
  int i = blockIdx.x * 256 + threadIdx.x;
  if (i < BATCH * SEQ) out[i] = bo2[0];
}

// finalize (PART path): out[e] = bo2 + sum_j part[e*32+j]; one thread per (b,t)
__global__ void __launch_bounds__(256, 1) finalize_ys_kernel(
    const float* __restrict__ part, float* __restrict__ out, const float* __restrict__ bo2) {
  int e = blockIdx.x * 256 + threadIdx.x;           // 512 blocks x 256 = BATCH*SEQ
  const float4* p = (const float4*)(part + (size_t)e * 32);
  float s = 0.f;
#pragma unroll
  for (int q = 0; q < 8; ++q) { float4 v = p[q]; s += v.x + v.y + v.z + v.w; }
  out[e] = bo2[0] + s;
}

template<bool PART>
__global__ void __launch_bounds__(128, 1) gru_persist(
    const float* __restrict__ x,  const float* __restrict__ Wg, const float* __restrict__ bg,
    const float* __restrict__ Wh, const float* __restrict__ bh,
    const float* __restrict__ Wo1,const float* __restrict__ bo1,
    const float* __restrict__ Wo2,const float* __restrict__ bo2,
    float* __restrict__ out, char* __restrict__ ws, float* __restrict__ ypart)
{
  extern __shared__ char smem[];
  const int bid  = blockIdx.x;
  const int gi   = bid & 7;        // group; bid&7 keeps group's x rows on one XCD L2 (perf-only)
  const int j    = bid >> 3;       // 0..31 within group
  const int tid  = threadIdx.x;
  const int lane = tid & 63;
  const int mt   = tid >> 6;       // wave 0,1 = M-tile
  const int rowbase = gi * RPG;
  const int colbase = j * CPW;

  short* hbf  = (short*)(ws + HBF_OFF);
  short* rhbf = (short*)(ws + RHBF_OFF);
  uint32_t* fA = (uint32_t*)(ws + (size_t)gi * 512);
  uint32_t* fB = (uint32_t*)(ws + (size_t)gi * 512 + 256);
  const uint32_t* fAmine = fA + mt * 32;   // this wave's producers (same mt-half)
  const uint32_t* fBmine = fB + mt * 32;
  uint32_t* myA = fA + (mt * 32 + j);
  uint32_t* myB = fB + (mt * 32 + j);

  // ---------------- init: weights -> LDS (128 threads, one-time) ----------------
  for (int it = 0; it < 256; ++it) {
    int cc = tid & 31;
    int k = (tid >> 5) + it * 4;
    int cg = (cc < 16) ? (colbase + cc) : (512 + colbase + (cc - 16));
    *(short*)(smem + wgs_off(cc, k)) = f2bf(Wg[(size_t)k * 1024 + cg]);
  }
  for (int it = 0; it < 128; ++it) {
    int cc = tid & 15;
    int k = (tid >> 4) + it * 8;
    *(short*)(smem + whs_off(cc, k)) = f2bf(Wh[(size_t)k * 512 + colbase + cc]);
  }
  for (int it = 0; it < 64; ++it) {
    int cc = tid & 15;
    int k = (tid >> 4) + it * 8;
    *(short*)(smem + wo1_off(cc, k)) = (cc < 8) ? f2bf(Wo1[(size_t)k * 256 + j * 8 + cc]) : (short)0;
  }

  const int lc = lane & 15;
  const float bgu  = bg[colbase + lc];
  const float bgr  = bg[512 + colbase + lc];
  const float bhc  = bh[colbase + lc];
  const float bo1c = (lc < 8) ? bo1[j * 8 + lc] : 0.f;
  const float wo2c = (lc < 8) ? Wo2[j * 8 + lc] : 0.f;
  __syncthreads();   // the ONLY block barrier

  const int arow  = mt * 16 + lc;          // A-frag row (local)
  const int kl    = (lane >> 4) * 8;       // frag k sub-offset (elements)
  const int xpose = XPOSE_OFF + mt * 640;
  const int grow  = rowbase + mt * 16;

  const char* hfrag  = (const char*)(hbf  + (size_t)(rowbase + arow) * HDIM + kl);
  const char* rhfrag = (const char*)(rhbf + (size_t)(rowbase + arow) * HDIM + kl);

  float hreg[4] = {0.f, 0.f, 0.f, 0.f};
  for (int t = 0; t < SEQ; ++t) {
    // ---- x A-frags (plain C f2bf: compiler clusters the 32 loads) + gates-x MFMAs ----
    bf16x8 xa[16];
    {
      const float* xrow = x + ((size_t)(rowbase + arow) * SEQ + t) * IDIM + kl;
#pragma unroll
      for (int ks = 0; ks < 16; ++ks) {
        float4 a = *(const float4*)(xrow + ks * 32);
        float4 b = *(const float4*)(xrow + ks * 32 + 4);
        bf16x8 v;
        v[0] = f2bf(a.x); v[1] = f2bf(a.y); v[2] = f2bf(a.z); v[3] = f2bf(a.w);
        v[4] = f2bf(b.x); v[5] = f2bf(b.y); v[6] = f2bf(b.z); v[7] = f2bf(b.w);
        xa[ks] = v;
      }
    }
    f32x4 gu0 = {0,0,0,0}, gu1 = {0,0,0,0}, gr0 = {0,0,0,0}, gr1 = {0,0,0,0};
#pragma unroll
    for (int ks = 0; ks < 16; ks += 2) {
      gu0 = MFMA(xa[ks],   LDB(wgs_off(lc, ks * 32 + kl)),            gu0);
      gu1 = MFMA(xa[ks+1], LDB(wgs_off(lc, (ks + 1) * 32 + kl)),      gu1);
      gr0 = MFMA(xa[ks],   LDB(wgs_off(16 + lc, ks * 32 + kl)),       gr0);
      gr1 = MFMA(xa[ks+1], LDB(wgs_off(16 + lc, (ks + 1) * 32 + kl)), gr1);
    }
    // ---- hop B: h_{t-1} ----
    i32x4 ha[16];
    if (t) {
      poll32(fBmine, (uint32_t)t);
      GLD_ALL16(ha, hfrag);
#pragma unroll
      for (int ks = 0; ks < 16; ks += 2) {
        gu0 = MFMA(asbf(ha[ks]),   LDB(wgs_off(lc, 512 + ks * 32 + kl)),            gu0);
        gu1 = MFMA(asbf(ha[ks+1]), LDB(wgs_off(lc, 512 + (ks + 1) * 32 + kl)),      gu1);
        gr0 = MFMA(asbf(ha[ks]),   LDB(wgs_off(16 + lc, 512 + ks * 32 + kl)),       gr0);
        gr1 = MFMA(asbf(ha[ks+1]), LDB(wgs_off(16 + lc, 512 + (ks + 1) * 32 + kl)), gr1);
      }
    }
    f32x4 gu = gu0 + gu1, gr = gr0 + gr1;
    float uv[4], rhv[4];
#pragma unroll
    for (int ri = 0; ri < 4; ++ri) {
      uv[ri]  = sigm(gu[ri] + bgu);
      rhv[ri] = sigm(gr[ri] + bgr) * hreg[ri];
    }
    if (t) {   // rh(0)=0 group-wide: no publish/consume at t=0
      publish16x16(smem, xpose, rhbf, grow, colbase, lane, rhv);
      flag_pub(myA, (uint32_t)(t + 1));
    }
    // ---- fA shadow: head MFMAs + cand-x MFMAs ----
    f32x4 hd0 = {0,0,0,0}, hd1 = {0,0,0,0};
    if (t) {
#pragma unroll
      for (int ks = 0; ks < 16; ks += 2) {
        hd0 = MFMA(asbf(ha[ks]),   LDB(wo1_off(lc, ks * 32 + kl)),       hd0);
        hd1 = MFMA(asbf(ha[ks+1]), LDB(wo1_off(lc, (ks + 1) * 32 + kl)), hd1);
      }
    }
    f32x4 cx0 = {0,0,0,0}, cx1 = {0,0,0,0};
#pragma unroll
    for (int ks = 0; ks < 16; ks += 2) {
      cx0 = MFMA(xa[ks],   LDB(whs_off(lc, ks * 32 + kl)),       cx0);
      cx1 = MFMA(xa[ks+1], LDB(whs_off(lc, (ks + 1) * 32 + kl)), cx1);
    }
    // ---- hop A: r*h ----
    f32x4 ch0 = {0,0,0,0}, ch1 = {0,0,0,0};
    if (t) {
      poll32(fAmine, (uint32_t)(t + 1));
      i32x4 ra[16];
      GLD_ALL16(ra, rhfrag);
#pragma unroll
      for (int ks = 0; ks < 16; ks += 2) {
        ch0 = MFMA(asbf(ra[ks]),   LDB(whs_off(lc, 512 + ks * 32 + kl)),       ch0);
        ch1 = MFMA(asbf(ra[ks+1]), LDB(whs_off(lc, 512 + (ks + 1) * 32 + kl)), ch1);
      }
    }
    // ---- h update ----
    f32x4 cc = cx0 + cx1 + ch0 + ch1;
    float hnv[4];
#pragma unroll
    for (int ri = 0; ri < 4; ++ri) {
      float cand = tanhf(cc[ri] + bhc);
      float hnew = hreg[ri] + uv[ri] * (cand - hreg[ri]);
      hreg[ri] = hnew; hnv[ri] = hnew;
      if (t == SEQ - 1) {
        int row = mt * 16 + (lane >> 4) * 4 + ri;
        out[(size_t)(BATCH * SEQ) + (size_t)(rowbase + row) * HDIM + colbase + lc] = hnew;
      }
    }
    publish16x16(smem, xpose, hbf, grow, colbase, lane, hnv);
    flag_pub(myB, (uint32_t)(t + 1));
    // ---- finish head y_{t-1}: shuffles + partial-store/atomic (off the drain path) ----
    if (t) {
      f32x4 d = hd0 + hd1;
#pragma unroll
      for (int ri = 0; ri < 4; ++ri) {
        float z = fmaxf(d[ri] + bo1c, 0.f) * wo2c;
        z += __shfl_xor(z, 1); z += __shfl_xor(z, 2);
        z += __shfl_xor(z, 4); z += __shfl_xor(z, 8);
        if (lc == 0) {
          int row = rowbase + mt * 16 + (lane >> 4) * 4 + ri;
          if constexpr (PART)
            ypart[((size_t)row * SEQ + (t - 1)) * 32 + j] = z;   // plain cached store
          else
            unsafeAtomicAdd(&out[(size_t)row * SEQ + (t - 1)], z);
        }
      }
    }
  }
  // ---- epilogue: y_{SEQ-1} ----
  poll32(fBmine, (uint32_t)SEQ);
  i32x4 ha[16];
  GLD_ALL16(ha, hfrag);
  f32x4 hd0 = {0,0,0,0}, hd1 = {0,0,0,0};
#pragma unroll
  for (int ks = 0; ks < 16; ks += 2) {
    hd0 = MFMA(asbf(ha[ks]),   LDB(wo1_off(lc, ks * 32 + kl)),       hd0);
    hd1 = MFMA(asbf(ha[ks+1]), LDB(wo1_off(lc, (ks + 1) * 32 + kl)), hd1);
  }
  f32x4 d = hd0 + hd1;
#pragma unroll
  for (int ri = 0; ri < 4; ++ri) {
    float z = fmaxf(d[ri] + bo1c, 0.f) * wo2c;
    z += __shfl_xor(z, 1); z += __shfl_xor(z, 2);
    z += __shfl_xor(z, 4); z += __shfl_xor(z, 8);
    if (lc == 0) {
      int row = rowbase + mt * 16 + (lane >> 4) * 4 + ri;
      if constexpr (PART)
        ypart[((size_t)row * SEQ + (SEQ - 1)) * 32 + j] = z;
      else
        unsafeAtomicAdd(&out[(size_t)row * SEQ + (SEQ - 1)], z);
    }
  }
}

extern "C" void kernel_launch(void* const* d_in, const int* in_sizes, int n_in,
                              void* d_out, int out_size, void* d_ws, size_t ws_size,
                              hipStream_t stream) {
  const float* x   = (const float*)d_in[0];
  const float* Wg  = (const float*)d_in[1];
  const float* bg  = (const float*)d_in[2];
  const float* Wh  = (const float*)d_in[3];
  const float* bh  = (const float*)d_in[4];
  const float* Wo1 = (const float*)d_in[5];
  const float* bo1 = (const float*)d_in[6];
  const float* Wo2 = (const float*)d_in[7];
  const float* bo2 = (const float*)d_in[8];
  float* out = (float*)d_out;
  char*  ws  = (char*)d_ws;
  if (ws_size < WS_ATOM) return;

  const bool part = (ws_size >= WS_PART);
  float* ypart = (float*)(ws + YP_OFF);

  hipMemsetAsync(ws, 0, WS_ZERO, stream);      // flag arrays
  if (!part)
    init_ys_kernel<<<dim3(512), dim3(256), 0, stream>>>(out, bo2);

  if (part) {
    (void)hipFuncSetAttribute((const void*)gru_persist<true>,
                              hipFuncAttributeMaxDynamicSharedMemorySize, SMEM_BYTES);
    gru_persist<true><<<dim3(NG * WC), dim3(128), SMEM_BYTES, stream>>>(
        x, Wg, bg, Wh, bh, Wo1, bo1, Wo2, bo2, out, ws, ypart);
    finalize_ys_kernel<<<dim3(512), dim3(256), 0, stream>>>(ypart, out, bo2);
  } else {
    (void)hipFuncSetAttribute((const void*)gru_persist<false>,
                              hipFuncAttributeMaxDynamicSharedMemorySize, SMEM_BYTES);
    gru_persist<false><<<dim3(NG * WC), dim3(128), SMEM_BYTES, stream>>>(
        x, Wg, bg, Wh, bh, Wo1, bo1, Wo2, bo2, out, ws, ypart);
  }
}

// Round 16
// 4243.841 us; speedup vs baseline: 1.9813x; 1.0247x over previous
//
#include <hip/hip_runtime.h>
#include <hip/hip_bf16.h>
#include <stdint.h>

typedef float f32x4 __attribute__((ext_vector_type(4)));
typedef short bf16x8 __attribute__((ext_vector_type(8)));
typedef int   i32x4  __attribute__((ext_vector_type(4)));

#define DEVINL static __device__ __forceinline__

// ---------------- problem dims ----------------
constexpr int BATCH = 256, SEQ = 512, IDIM = 512, HDIM = 512;
constexpr int NG = 8, WC = 32, RPG = 32, CPW = 16;

// ---------------- LDS map (bytes) ----------------
constexpr int WGS_OFF = 0;        // Wg stripe [32 cols][1024 k] bf16 (64KB), XOR-swizzled
constexpr int WHS_OFF = 65536;    // Wh stripe [16 cols][1024 k] bf16 (32KB)
constexpr int WO1_OFF = 98304;    // Wo1 stripe [16 cols][512 k] bf16 (16KB, cols 8..15 zero)
constexpr int XPOSE_OFF = 114688; // 2 waves x 640B repack buffers
constexpr int SMEM_BYTES = XPOSE_OFF + 2 * 640;   // 115968

// ---------------- ws map (bytes) ----------------
// flags per group (512B region): fA u32[mt*32+j] at +0, fB at +256
constexpr size_t WS_ZERO  = 4096;             // flag arrays (memset each call)
constexpr size_t HBF_OFF  = 8192;             // bf16 h   [256][512] (256KB), no init needed
constexpr size_t RHBF_OFF = HBF_OFF + 262144; // bf16 r*h [256][512] (256KB), no init needed
constexpr size_t WS_ATOM  = RHBF_OFF + 262144;        // r8 footprint (~0.53MB)
constexpr size_t YP_OFF   = WS_ATOM;                  // fp32 partials [256][512][32] (16.8MB)
constexpr size_t WS_PART  = YP_OFF + (size_t)BATCH * SEQ * 32 * 4;

DEVINL short f2bf(float f) {
  uint32_t u = __float_as_uint(f);
  u += 0x7FFFu + ((u >> 16) & 1u);   // RNE
  return (short)(u >> 16);
}
DEVINL int wgs_off(int c, int k) { return WGS_OFF + c * 2048 + ((k * 2) ^ ((c & 7) << 4)); }
DEVINL int whs_off(int c, int k) { return WHS_OFF + c * 2048 + ((k * 2) ^ ((c & 7) << 4)); }
DEVINL int wo1_off(int c, int k) { return WO1_OFF + c * 1024 + ((k * 2) ^ ((c & 7) << 4)); }
DEVINL float sigm(float v) { return 1.f / (1.f + __expf(-v)); }
DEVINL bf16x8 asbf(i32x4 v) { return __builtin_bit_cast(bf16x8, v); }

// ---------------- flag / exchange primitives (agent scope: sc1) — r8-proven ----------------
DEVINL void flag_pub(uint32_t* p, uint32_t v) {
  asm volatile("s_waitcnt vmcnt(0) lgkmcnt(0)\n\tglobal_store_dword %0, %1, off sc1"
               :: "v"(p), "v"(v) : "memory");
}
// poll own 32-slot region (2 cache lines). Adaptive throttle + bounded.
DEVINL void poll32(const uint32_t* base, uint32_t target) {
  const uint32_t* p = base + (threadIdx.x & 31);
  int iter = 0;
  for (;;) {
    uint32_t v;
    asm volatile("global_load_dword %0, %1, off sc1\n\ts_waitcnt vmcnt(0)"
                 : "=v"(v) : "v"(p) : "memory");
    if (__all((int)(v >= target))) break;
    if (++iter > 20000) break;           // bounded: pathology -> fast fail, not timeout
    if (iter > 4) __builtin_amdgcn_s_sleep(1);   // fast-spin first, then throttle
  }
  __builtin_amdgcn_sched_barrier(0);
}
// repack 16x16 bf16 tile through private LDS slice -> 8B/lane store (issue only)
DEVINL void publish16x16(char* smem, int xpose, short* dst, int grow, int colbase,
                         int lane, const float* vals) {
  const int q = lane >> 4, lc = lane & 15;
#pragma unroll
  for (int ri = 0; ri < 4; ++ri)
    *(short*)(smem + xpose + (q * 4 + ri) * 40 + lc * 2) = f2bf(vals[ri]);
  asm volatile("s_waitcnt lgkmcnt(0)" ::: "memory");
  __builtin_amdgcn_sched_barrier(0);
  const int rl = lane >> 2, cq = lane & 3;
  unsigned long long d = *(const unsigned long long*)(smem + xpose + rl * 40 + cq * 8);
  short* gp = dst + (size_t)(grow + rl) * HDIM + colbase + cq * 4;
  asm volatile("global_store_dwordx2 %0, %1, off sc1" :: "v"(gp), "v"(d) : "memory");
}
// exchange-fragment gathers (sc1) — 16 x 16B, one fence
#define GLD16(dst, ptr, imm) \
  asm volatile("global_load_dwordx4 %0, %1, off offset:" imm " sc1" : "=v"(dst) : "v"(ptr))
#define GLD_ALL16(arr, ptr) do { \
  GLD16(arr[0],  ptr, "0");   GLD16(arr[1],  ptr, "64");  \
  GLD16(arr[2],  ptr, "128"); GLD16(arr[3],  ptr, "192"); \
  GLD16(arr[4],  ptr, "256"); GLD16(arr[5],  ptr, "320"); \
  GLD16(arr[6],  ptr, "384"); GLD16(arr[7],  ptr, "448"); \
  GLD16(arr[8],  ptr, "512"); GLD16(arr[9],  ptr, "576"); \
  GLD16(arr[10], ptr, "640"); GLD16(arr[11], ptr, "704"); \
  GLD16(arr[12], ptr, "768"); GLD16(arr[13], ptr, "832"); \
  GLD16(arr[14], ptr, "896"); GLD16(arr[15], ptr, "960"); \
  asm volatile("s_waitcnt vmcnt(0)" ::: "memory"); \
  __builtin_amdgcn_sched_barrier(0); \
} while (0)

#define MFMA(a, b, c) __builtin_amdgcn_mfma_f32_16x16x32_bf16((a), (b), (c), 0, 0, 0)
#define LDB(off) (*(const bf16x8*)(smem + (off)))

__global__ void __launch_bounds__(256, 1) init_ys_kernel(float* out, const float* bo2) {
  int i = blockIdx.x * 256 + threadIdx.x;
  if (i < BATCH * SEQ) out[i] = bo2[0];
}

// finalize (PART path): out[e] = bo2 + sum_j part[e*32+j]; one thread per (b,t)
__global__ void __launch_bounds__(256, 1) finalize_ys_kernel(
    const float* __restrict__ part, float* __restrict__ out, const float* __restrict__ bo2) {
  int e = blockIdx.x * 256 + threadIdx.x;           // 512 blocks x 256 = BATCH*SEQ
  const float4* p = (const float4*)(part + (size_t)e * 32);
  float s = 0.f;
#pragma unroll
  for (int q = 0; q < 8; ++q) { float4 v = p[q]; s += v.x + v.y + v.z + v.w; }
  out[e] = bo2[0] + s;
}

template<bool PART>
__global__ void __launch_bounds__(128, 1) gru_persist(
    const float* __restrict__ x,  const float* __restrict__ Wg, const float* __restrict__ bg,
    const float* __restrict__ Wh, const float* __restrict__ bh,
    const float* __restrict__ Wo1,const float* __restrict__ bo1,
    const float* __restrict__ Wo2,const float* __restrict__ bo2,
    float* __restrict__ out, char* __restrict__ ws, float* __restrict__ ypart)
{
  extern __shared__ char smem[];
  const int bid  = blockIdx.x;
  const int gi   = bid & 7;        // group; bid&7 keeps group's x rows on one XCD L2 (perf-only)
  const int j    = bid >> 3;       // 0..31 within group
  const int tid  = threadIdx.x;
  const int lane = tid & 63;
  const int mt   = tid >> 6;       // wave 0,1 = M-tile
  const int rowbase = gi * RPG;
  const int colbase = j * CPW;

  short* hbf  = (short*)(ws + HBF_OFF);
  short* rhbf = (short*)(ws + RHBF_OFF);
  uint32_t* fA = (uint32_t*)(ws + (size_t)gi * 512);
  uint32_t* fB = (uint32_t*)(ws + (size_t)gi * 512 + 256);
  const uint32_t* fAmine = fA + mt * 32;   // this wave's producers (same mt-half)
  const uint32_t* fBmine = fB + mt * 32;
  uint32_t* myA = fA + (mt * 32 + j);
  uint32_t* myB = fB + (mt * 32 + j);

  // ---------------- init: weights -> LDS (128 threads, one-time) ----------------
  for (int it = 0; it < 256; ++it) {
    int cc = tid & 31;
    int k = (tid >> 5) + it * 4;
    int cg = (cc < 16) ? (colbase + cc) : (512 + colbase + (cc - 16));
    *(short*)(smem + wgs_off(cc, k)) = f2bf(Wg[(size_t)k * 1024 + cg]);
  }
  for (int it = 0; it < 128; ++it) {
    int cc = tid & 15;
    int k = (tid >> 4) + it * 8;
    *(short*)(smem + whs_off(cc, k)) = f2bf(Wh[(size_t)k * 512 + colbase + cc]);
  }
  for (int it = 0; it < 64; ++it) {
    int cc = tid & 15;
    int k = (tid >> 4) + it * 8;
    *(short*)(smem + wo1_off(cc, k)) = (cc < 8) ? f2bf(Wo1[(size_t)k * 256 + j * 8 + cc]) : (short)0;
  }

  const int lc = lane & 15;
  const float bgu  = bg[colbase + lc];
  const float bgr  = bg[512 + colbase + lc];
  const float bhc  = bh[colbase + lc];
  const float bo1c = (lc < 8) ? bo1[j * 8 + lc] : 0.f;
  const float wo2c = (lc < 8) ? Wo2[j * 8 + lc] : 0.f;
  __syncthreads();   // the ONLY block barrier

  const int arow  = mt * 16 + lc;          // A-frag row (local)
  const int kl    = (lane >> 4) * 8;       // frag k sub-offset (elements)
  const int xpose = XPOSE_OFF + mt * 640;
  const int grow  = rowbase + mt * 16;

  const char* hfrag  = (const char*)(hbf  + (size_t)(rowbase + arow) * HDIM + kl);
  const char* rhfrag = (const char*)(rhbf + (size_t)(rowbase + arow) * HDIM + kl);

  float hreg[4] = {0.f, 0.f, 0.f, 0.f};
  for (int t = 0; t < SEQ; ++t) {
    // ---- x A-frags (plain C f2bf: compiler clusters the 32 loads) + gates-x MFMAs ----
    bf16x8 xa[16];
    {
      const float* xrow = x + ((size_t)(rowbase + arow) * SEQ + t) * IDIM + kl;
#pragma unroll
      for (int ks = 0; ks < 16; ++ks) {
        float4 a = *(const float4*)(xrow + ks * 32);
        float4 b = *(const float4*)(xrow + ks * 32 + 4);
        bf16x8 v;
        v[0] = f2bf(a.x); v[1] = f2bf(a.y); v[2] = f2bf(a.z); v[3] = f2bf(a.w);
        v[4] = f2bf(b.x); v[5] = f2bf(b.y); v[6] = f2bf(b.z); v[7] = f2bf(b.w);
        xa[ks] = v;
      }
    }
    f32x4 gu0 = {0,0,0,0}, gu1 = {0,0,0,0}, gr0 = {0,0,0,0}, gr1 = {0,0,0,0};
#pragma unroll
    for (int ks = 0; ks < 16; ks += 2) {
      gu0 = MFMA(xa[ks],   LDB(wgs_off(lc, ks * 32 + kl)),            gu0);
      gu1 = MFMA(xa[ks+1], LDB(wgs_off(lc, (ks + 1) * 32 + kl)),      gu1);
      gr0 = MFMA(xa[ks],   LDB(wgs_off(16 + lc, ks * 32 + kl)),       gr0);
      gr1 = MFMA(xa[ks+1], LDB(wgs_off(16 + lc, (ks + 1) * 32 + kl)), gr1);
    }
    // ---- hop B: h_{t-1} -> RESET gate only (shortest path to flagA) ----
    i32x4 ha[16];
    if (t) {
      poll32(fBmine, (uint32_t)t);
      GLD_ALL16(ha, hfrag);
#pragma unroll
      for (int ks = 0; ks < 16; ks += 2) {
        gr0 = MFMA(asbf(ha[ks]),   LDB(wgs_off(16 + lc, 512 + ks * 32 + kl)),       gr0);
        gr1 = MFMA(asbf(ha[ks+1]), LDB(wgs_off(16 + lc, 512 + (ks + 1) * 32 + kl)), gr1);
      }
    }
    f32x4 gr = gr0 + gr1;
    float rhv[4];
#pragma unroll
    for (int ri = 0; ri < 4; ++ri) rhv[ri] = sigm(gr[ri] + bgr) * hreg[ri];
    if (t) {   // rh(0)=0 group-wide: no publish/consume at t=0
      publish16x16(smem, xpose, rhbf, grow, colbase, lane, rhv);
      flag_pub(myA, (uint32_t)(t + 1));
    }
    // ---- pollA-window filler (LDS/MFMA only): update-gate h-part, head, cand-x ----
    if (t) {
#pragma unroll
      for (int ks = 0; ks < 16; ks += 2) {
        gu0 = MFMA(asbf(ha[ks]),   LDB(wgs_off(lc, 512 + ks * 32 + kl)),       gu0);
        gu1 = MFMA(asbf(ha[ks+1]), LDB(wgs_off(lc, 512 + (ks + 1) * 32 + kl)), gu1);
      }
    }
    f32x4 gu = gu0 + gu1;
    float uv[4];
#pragma unroll
    for (int ri = 0; ri < 4; ++ri) uv[ri] = sigm(gu[ri] + bgu);
    f32x4 hd0 = {0,0,0,0}, hd1 = {0,0,0,0};
    if (t) {
#pragma unroll
      for (int ks = 0; ks < 16; ks += 2) {
        hd0 = MFMA(asbf(ha[ks]),   LDB(wo1_off(lc, ks * 32 + kl)),       hd0);
        hd1 = MFMA(asbf(ha[ks+1]), LDB(wo1_off(lc, (ks + 1) * 32 + kl)), hd1);
      }
    }
    f32x4 cx0 = {0,0,0,0}, cx1 = {0,0,0,0};
#pragma unroll
    for (int ks = 0; ks < 16; ks += 2) {
      cx0 = MFMA(xa[ks],   LDB(whs_off(lc, ks * 32 + kl)),       cx0);
      cx1 = MFMA(xa[ks+1], LDB(whs_off(lc, (ks + 1) * 32 + kl)), cx1);
    }
    // ---- hop A: r*h -> cand-h ----
    f32x4 ch0 = {0,0,0,0}, ch1 = {0,0,0,0};
    if (t) {
      poll32(fAmine, (uint32_t)(t + 1));
      i32x4 ra[16];
      GLD_ALL16(ra, rhfrag);
#pragma unroll
      for (int ks = 0; ks < 16; ks += 2) {
        ch0 = MFMA(asbf(ra[ks]),   LDB(whs_off(lc, 512 + ks * 32 + kl)),       ch0);
        ch1 = MFMA(asbf(ra[ks+1]), LDB(whs_off(lc, 512 + (ks + 1) * 32 + kl)), ch1);
      }
    }
    // ---- h update ----
    f32x4 cc = cx0 + cx1 + ch0 + ch1;
    float hnv[4];
#pragma unroll
    for (int ri = 0; ri < 4; ++ri) {
      float cand = tanhf(cc[ri] + bhc);
      float hnew = hreg[ri] + uv[ri] * (cand - hreg[ri]);
      hreg[ri] = hnew; hnv[ri] = hnew;
      if (t == SEQ - 1) {
        int row = mt * 16 + (lane >> 4) * 4 + ri;
        out[(size_t)(BATCH * SEQ) + (size_t)(rowbase + row) * HDIM + colbase + lc] = hnew;
      }
    }
    publish16x16(smem, xpose, hbf, grow, colbase, lane, hnv);
    flag_pub(myB, (uint32_t)(t + 1));
    // ---- finish head y_{t-1}: shuffles + partial-store/atomic (off the drain path) ----
    if (t) {
      f32x4 d = hd0 + hd1;
#pragma unroll
      for (int ri = 0; ri < 4; ++ri) {
        float z = fmaxf(d[ri] + bo1c, 0.f) * wo2c;
        z += __shfl_xor(z, 1); z += __shfl_xor(z, 2);
        z += __shfl_xor(z, 4); z += __shfl_xor(z, 8);
        if (lc == 0) {
          int row = rowbase + mt * 16 + (lane >> 4) * 4 + ri;
          if constexpr (PART)
            ypart[((size_t)row * SEQ + (t - 1)) * 32 + j] = z;   // plain cached store
          else
            unsafeAtomicAdd(&out[(size_t)row * SEQ + (t - 1)], z);
        }
      }
    }
  }
  // ---- epilogue: y_{SEQ-1} ----
  poll32(fBmine, (uint32_t)SEQ);
  i32x4 ha[16];
  GLD_ALL16(ha, hfrag);
  f32x4 hd0 = {0,0,0,0}, hd1 = {0,0,0,0};
#pragma unroll
  for (int ks = 0; ks < 16; ks += 2) {
    hd0 = MFMA(asbf(ha[ks]),   LDB(wo1_off(lc, ks * 32 + kl)),       hd0);
    hd1 = MFMA(asbf(ha[ks+1]), LDB(wo1_off(lc, (ks + 1) * 32 + kl)), hd1);
  }
  f32x4 d = hd0 + hd1;
#pragma unroll
  for (int ri = 0; ri < 4; ++ri) {
    float z = fmaxf(d[ri] + bo1c, 0.f) * wo2c;
    z += __shfl_xor(z, 1); z += __shfl_xor(z, 2);
    z += __shfl_xor(z, 4); z += __shfl_xor(z, 8);
    if (lc == 0) {
      int row = rowbase + mt * 16 + (lane >> 4) * 4 + ri;
      if constexpr (PART)
        ypart[((size_t)row * SEQ + (SEQ - 1)) * 32 + j] = z;
      else
        unsafeAtomicAdd(&out[(size_t)row * SEQ + (SEQ - 1)], z);
    }
  }
}

extern "C" void kernel_launch(void* const* d_in, const int* in_sizes, int n_in,
                              void* d_out, int out_size, void* d_ws, size_t ws_size,
                              hipStream_t stream) {
  const float* x   = (const float*)d_in[0];
  const float* Wg  = (const float*)d_in[1];
  const float* bg  = (const float*)d_in[2];
  const float* Wh  = (const float*)d_in[3];
  const float* bh  = (const float*)d_in[4];
  const float* Wo1 = (const float*)d_in[5];
  const float* bo1 = (const float*)d_in[6];
  const float* Wo2 = (const float*)d_in[7];
  const float* bo2 = (const float*)d_in[8];
  float* out = (float*)d_out;
  char*  ws  = (char*)d_ws;
  if (ws_size < WS_ATOM) return;

  const bool part = (ws_size >= WS_PART);
  float* ypart = (float*)(ws + YP_OFF);

  hipMemsetAsync(ws, 0, WS_ZERO, stream);      // flag arrays
  if (!part)
    init_ys_kernel<<<dim3(512), dim3(256), 0, stream>>>(out, bo2);

  if (part) {
    (void)hipFuncSetAttribute((const void*)gru_persist<true>,
                              hipFuncAttributeMaxDynamicSharedMemorySize, SMEM_BYTES);
    gru_persist<true><<<dim3(NG * WC), dim3(128), SMEM_BYTES, stream>>>(
        x, Wg, bg, Wh, bh, Wo1, bo1, Wo2, bo2, out, ws, ypart);
    finalize_ys_kernel<<<dim3(512), dim3(256), 0, stream>>>(ypart, out, bo2);
  } else {
    (void)hipFuncSetAttribute((const void*)gru_persist<false>,
                              hipFuncAttributeMaxDynamicSharedMemorySize, SMEM_BYTES);
    gru_persist<false><<<dim3(NG * WC), dim3(128), SMEM_BYTES, stream>>>(
        x, Wg, bg, Wh, bh, Wo1, bo1, Wo2, bo2, out, ws, ypart);
  }
}